// Round 24
// baseline (40.992 us; speedup 1.0000x reference)
//
#include <hip/hip_runtime.h>
#include <hip/hip_bf16.h>
#include <hip/hip_fp16.h>
#include <cfloat>

// Problem constants
#define BB   16
#define LL   4096
#define CC   9
#define DIN  512
#define DOUT 128
#define VV   96

// LDS layout (halves): padded row strides (round-8 verified)
#define PWLD 520    // 512 + 8
#define PELD 136    // 128 + 8

typedef _Float16 h2 __attribute__((ext_vector_type(2)));

#if defined(__has_builtin)
#if __has_builtin(__builtin_amdgcn_fdot2)
#define FDOT2(a, b, c) __builtin_amdgcn_fdot2((a), (b), (c), false)
#endif
#endif
#ifndef FDOT2
__device__ __forceinline__ float FDOT2(h2 a, h2 b, float c) {
    return c + (float)a[0] * (float)b[0] + (float)a[1] * (float)b[1];
}
#endif

__device__ __forceinline__ h2 pack_h2(float lo, float hi) {
    return __builtin_bit_cast(h2, __builtin_amdgcn_cvt_pkrtz(lo, hi));
}

// ---------------------------------------------------------------------------
// Kernel 1: PW[v][k] = sum_o PE[v][o]*W[o][k] -> fp16; y==0 also converts PEh.
// ---------------------------------------------------------------------------
__global__ __launch_bounds__(128)
void pw_kernel(const float* __restrict__ W,    // [DOUT][DIN]
               const float* __restrict__ PE,   // [VV][DOUT]
               __half*      __restrict__ PW,   // [VV][DIN]
               __half*      __restrict__ PEh)  // [VV][DOUT]
{
    const int v = blockIdx.x;                       // 0..95
    const int k = blockIdx.y * 128 + threadIdx.x;   // 0..511
    const float* per = PE + v * DOUT;
    float a = 0.f;
    #pragma unroll 8
    for (int o = 0; o < DOUT; ++o)
        a = fmaf(per[o], W[(size_t)o * DIN + k], a);
    PW[(size_t)v * DIN + k] = __float2half_rn(a);
    if (blockIdx.y == 0)
        PEh[(size_t)v * DOUT + threadIdx.x] = __float2half_rn(per[threadIdx.x]);
}

// ---------------------------------------------------------------------------
// Kernel 2: round-8 structure (best known): PW + PEh staged in LDS;
// 16 lanes/row; 1024 thr = 64 row-slots; 128 rows/block over 2 iterations.
// Dead rows (pad / no-candidate) skip the X stream and store zeros.
// ---------------------------------------------------------------------------
__global__ __launch_bounds__(1024)
void attn_kernel(const float*  __restrict__ X,     // [B*L][DIN]
                 const __half* __restrict__ PW,    // [VV][DIN]
                 const __half* __restrict__ PEh,   // [VV][DOUT]
                 const int*    __restrict__ CIDX,  // [B*L][CC]
                 const int*    __restrict__ CMASK, // [B*L][CC]
                 const int*    __restrict__ SLEN,  // [B]
                 float*        __restrict__ OUT)   // [B*L][DOUT]
{
    __shared__ __half lds_pw[VV * PWLD];   // 99840 B
    __shared__ __half lds_pe[VV * PELD];   // 26112 B

    const int t = threadIdx.x;

    // ---- stage PW: 96*512/8 = 6144 uint4 chunks, 6 per thread ----
    #pragma unroll
    for (int it = 0; it < 6; ++it) {
        int chunk = t + it * 1024;
        int v = chunk >> 6, kq = chunk & 63;
        uint4 d = *(const uint4*)(PW + (size_t)v * DIN + kq * 8);
        *(uint4*)&lds_pw[v * PWLD + kq * 8] = d;
    }
    // ---- stage PEh: 96*128/8 = 1536 chunks ----
    {
        if (t < 1536) {
            int v = t >> 4, kq = t & 15;
            *(uint4*)&lds_pe[v * PELD + kq * 8] =
                *(const uint4*)(PEh + (size_t)v * DOUT + kq * 8);
        }
        int c2 = t + 1024;
        if (c2 < 1536) {
            int v2 = c2 >> 4, k2 = c2 & 15;
            *(uint4*)&lds_pe[v2 * PELD + k2 * 8] =
                *(const uint4*)(PEh + (size_t)v2 * DOUT + k2 * 8);
        }
    }
    __syncthreads();

    const int lane = t & 63;
    const int il   = lane & 15;          // lane within row-group
    const int slot = t >> 4;             // 0..63 row-slot in block
    const int rowbase = blockIdx.x * 128;

    #pragma unroll
    for (int iter = 0; iter < 2; ++iter) {
        const int row = rowbase + iter * 64 + slot;
        const int  b     = row >> 12;
        const int  l     = row & (LL - 1);
        const bool inlen = l < SLEN[b];

        // ---- candidate indices + mask (cheap, L2/L3-hot) ----
        int ci[CC], vm[CC];
        #pragma unroll
        for (int c = 0; c < CC; ++c) ci[c]  = CIDX[(size_t)row * CC + c];
        #pragma unroll
        for (int c = 0; c < CC; ++c) vm[c] = CMASK[(size_t)row * CC + c];
        int anym = 0;
        #pragma unroll
        for (int c = 0; c < CC; ++c) anym |= vm[c];
        const bool alive = inlen && (anym != 0);

        float* op = OUT + (size_t)row * DOUT + il * 8;

        if (!alive) {
            // dead row: no X traffic, store zeros
            *(float4*)op       = make_float4(0.f, 0.f, 0.f, 0.f);
            *(float4*)(op + 4) = make_float4(0.f, 0.f, 0.f, 0.f);
        } else {
            // ---- X loads (the dominant HBM stream; only for live rows) ----
            const float* xr = X + (size_t)row * DIN;
            float4 xf[8];
            #pragma unroll
            for (int j = 0; j < 4; ++j) {
                xf[j * 2 + 0] = *(const float4*)(xr + il * 8 + 128 * j);
                xf[j * 2 + 1] = *(const float4*)(xr + il * 8 + 128 * j + 4);
            }
            h2 xh[16];
            #pragma unroll
            for (int q = 0; q < 8; ++q) {
                xh[q * 2 + 0] = pack_h2(xf[q].x, xf[q].y);
                xh[q * 2 + 1] = pack_h2(xf[q].z, xf[q].w);
            }

            // ---- scores from LDS PW ----
            float sc[CC];
            #pragma unroll
            for (int c = 0; c < CC; ++c) sc[c] = 0.f;
            #pragma unroll
            for (int j = 0; j < 4; ++j) {
                #pragma unroll
                for (int c = 0; c < CC; ++c) {
                    uint4 pwb = *(const uint4*)&lds_pw[ci[c] * PWLD + j * 128 + il * 8];
                    h2 p0 = __builtin_bit_cast(h2, pwb.x);
                    h2 p1 = __builtin_bit_cast(h2, pwb.y);
                    h2 p2 = __builtin_bit_cast(h2, pwb.z);
                    h2 p3 = __builtin_bit_cast(h2, pwb.w);
                    float s = sc[c];
                    s = FDOT2(xh[j * 4 + 0], p0, s);
                    s = FDOT2(xh[j * 4 + 1], p1, s);
                    s = FDOT2(xh[j * 4 + 2], p2, s);
                    s = FDOT2(xh[j * 4 + 3], p3, s);
                    sc[c] = s;
                }
            }
            #pragma unroll
            for (int c = 0; c < CC; ++c) {
                float s = sc[c];
                s += __shfl_xor(s, 1);
                s += __shfl_xor(s, 2);
                s += __shfl_xor(s, 4);
                s += __shfl_xor(s, 8);
                sc[c] = s;
            }

            // ---- masked softmax (redundant per lane) ----
            float mx = -FLT_MAX;
            #pragma unroll
            for (int c = 0; c < CC; ++c)
                if (vm[c]) mx = fmaxf(mx, sc[c]);
            float e[CC], den = 0.f;
            #pragma unroll
            for (int c = 0; c < CC; ++c) {
                e[c] = vm[c] ? __expf(sc[c] - mx) : 0.f;
                den += e[c];
            }
            const float scale = 1.f / den;

            // ---- weighted PE sum from LDS ----
            float o[8];
            #pragma unroll
            for (int j = 0; j < 8; ++j) o[j] = 0.f;
            #pragma unroll
            for (int c = 0; c < CC; ++c) {
                const float w = e[c];
                uint4 peb = *(const uint4*)&lds_pe[ci[c] * PELD + il * 8];
                h2 q0 = __builtin_bit_cast(h2, peb.x);
                h2 q1 = __builtin_bit_cast(h2, peb.y);
                h2 q2 = __builtin_bit_cast(h2, peb.z);
                h2 q3 = __builtin_bit_cast(h2, peb.w);
                o[0] = fmaf(w, (float)q0[0], o[0]); o[1] = fmaf(w, (float)q0[1], o[1]);
                o[2] = fmaf(w, (float)q1[0], o[2]); o[3] = fmaf(w, (float)q1[1], o[3]);
                o[4] = fmaf(w, (float)q2[0], o[4]); o[5] = fmaf(w, (float)q2[1], o[5]);
                o[6] = fmaf(w, (float)q3[0], o[6]); o[7] = fmaf(w, (float)q3[1], o[7]);
            }

            *(float4*)op       = make_float4(o[0] * scale, o[1] * scale, o[2] * scale, o[3] * scale);
            *(float4*)(op + 4) = make_float4(o[4] * scale, o[5] * scale, o[6] * scale, o[7] * scale);
        }
    }
}

extern "C" void kernel_launch(void* const* d_in, const int* in_sizes, int n_in,
                              void* d_out, int out_size, void* d_ws, size_t ws_size,
                              hipStream_t stream) {
    const float* X  = (const float*)d_in[0];
    const float* W  = (const float*)d_in[1];
    const float* PE = (const float*)d_in[2];
    const int*   CI = (const int*)d_in[3];
    const int*   CM = (const int*)d_in[4];
    const int*   SL = (const int*)d_in[5];
    float* OUT = (float*)d_out;
    __half* PW  = (__half*)d_ws;                       // 96*512*2 = 96 KiB
    __half* PEh = (__half*)d_ws + (size_t)VV * DIN;    // +96*128*2 = 24 KiB

    hipLaunchKernelGGL(pw_kernel, dim3(VV, 4), dim3(128), 0, stream, W, PE, PW, PEh);

    const int rows = BB * LL;            // 65536
    hipLaunchKernelGGL(attn_kernel, dim3(rows / 128), dim3(1024), 0, stream,
                       X, PW, PEh, CI, CM, SL, OUT);
}

// Round 25
// 38.078 us; speedup vs baseline: 1.0765x; 1.0765x over previous
//
#include <hip/hip_runtime.h>
#include <hip/hip_bf16.h>
#include <hip/hip_fp16.h>
#include <cfloat>

// Problem constants
#define BB   16
#define LL   4096
#define CC   9
#define DIN  512
#define DOUT 128
#define VV   96

// LDS layout (halves): padded row strides (round-8 verified)
#define PWLD 520    // 512 + 8
#define PELD 136    // 128 + 8

typedef _Float16 h2 __attribute__((ext_vector_type(2)));

#if defined(__has_builtin)
#if __has_builtin(__builtin_amdgcn_fdot2)
#define FDOT2(a, b, c) __builtin_amdgcn_fdot2((a), (b), (c), false)
#endif
#endif
#ifndef FDOT2
__device__ __forceinline__ float FDOT2(h2 a, h2 b, float c) {
    return c + (float)a[0] * (float)b[0] + (float)a[1] * (float)b[1];
}
#endif

__device__ __forceinline__ h2 pack_h2(float lo, float hi) {
    return __builtin_bit_cast(h2, __builtin_amdgcn_cvt_pkrtz(lo, hi));
}

// ---------------------------------------------------------------------------
// Kernel 1: PW[v][k] = sum_o PE[v][o]*W[o][k] -> fp16; y==0 also converts PEh.
// ---------------------------------------------------------------------------
__global__ __launch_bounds__(128)
void pw_kernel(const float* __restrict__ W,    // [DOUT][DIN]
               const float* __restrict__ PE,   // [VV][DOUT]
               __half*      __restrict__ PW,   // [VV][DIN]
               __half*      __restrict__ PEh)  // [VV][DOUT]
{
    const int v = blockIdx.x;                       // 0..95
    const int k = blockIdx.y * 128 + threadIdx.x;   // 0..511
    const float* per = PE + v * DOUT;
    float a = 0.f;
    #pragma unroll 8
    for (int o = 0; o < DOUT; ++o)
        a = fmaf(per[o], W[(size_t)o * DIN + k], a);
    PW[(size_t)v * DIN + k] = __float2half_rn(a);
    if (blockIdx.y == 0)
        PEh[(size_t)v * DOUT + threadIdx.x] = __float2half_rn(per[threadIdx.x]);
}

// ---------------------------------------------------------------------------
// Kernel 2: r19 winner, persistent form: grid 256 (1 block/CU), 256 rows per
// block over 4 barrier-free iterations (wave slip hides per-row chains).
// PW + PEh staged in LDS once; 16 lanes/row; dead rows skip the X stream.
// ---------------------------------------------------------------------------
__global__ __launch_bounds__(1024)
void attn_kernel(const float*  __restrict__ X,     // [B*L][DIN]
                 const __half* __restrict__ PW,    // [VV][DIN]
                 const __half* __restrict__ PEh,   // [VV][DOUT]
                 const int*    __restrict__ CIDX,  // [B*L][CC]
                 const int*    __restrict__ CMASK, // [B*L][CC]
                 const int*    __restrict__ SLEN,  // [B]
                 float*        __restrict__ OUT)   // [B*L][DOUT]
{
    __shared__ __half lds_pw[VV * PWLD];   // 99840 B
    __shared__ __half lds_pe[VV * PELD];   // 26112 B

    const int t = threadIdx.x;

    // ---- stage PW: 96*512/8 = 6144 uint4 chunks, 6 per thread ----
    #pragma unroll
    for (int it = 0; it < 6; ++it) {
        int chunk = t + it * 1024;
        int v = chunk >> 6, kq = chunk & 63;
        uint4 d = *(const uint4*)(PW + (size_t)v * DIN + kq * 8);
        *(uint4*)&lds_pw[v * PWLD + kq * 8] = d;
    }
    // ---- stage PEh: 96*128/8 = 1536 chunks ----
    {
        if (t < 1536) {
            int v = t >> 4, kq = t & 15;
            *(uint4*)&lds_pe[v * PELD + kq * 8] =
                *(const uint4*)(PEh + (size_t)v * DOUT + kq * 8);
        }
        int c2 = t + 1024;
        if (c2 < 1536) {
            int v2 = c2 >> 4, k2 = c2 & 15;
            *(uint4*)&lds_pe[v2 * PELD + k2 * 8] =
                *(const uint4*)(PEh + (size_t)v2 * DOUT + k2 * 8);
        }
    }
    __syncthreads();

    const int lane = t & 63;
    const int il   = lane & 15;          // lane within row-group
    const int slot = t >> 4;             // 0..63 row-slot in block
    const int rowbase = blockIdx.x * 256;

    #pragma unroll
    for (int iter = 0; iter < 4; ++iter) {
        const int row = rowbase + iter * 64 + slot;
        const int  b     = row >> 12;
        const int  l     = row & (LL - 1);
        const bool inlen = l < SLEN[b];

        // ---- candidate indices + mask (cheap, L2/L3-hot) ----
        int ci[CC], vm[CC];
        #pragma unroll
        for (int c = 0; c < CC; ++c) ci[c]  = CIDX[(size_t)row * CC + c];
        #pragma unroll
        for (int c = 0; c < CC; ++c) vm[c] = CMASK[(size_t)row * CC + c];
        int anym = 0;
        #pragma unroll
        for (int c = 0; c < CC; ++c) anym |= vm[c];
        const bool alive = inlen && (anym != 0);

        float* op = OUT + (size_t)row * DOUT + il * 8;

        if (!alive) {
            // dead row: no X traffic, store zeros
            *(float4*)op       = make_float4(0.f, 0.f, 0.f, 0.f);
            *(float4*)(op + 4) = make_float4(0.f, 0.f, 0.f, 0.f);
        } else {
            // ---- X loads (the dominant HBM stream; only for live rows) ----
            const float* xr = X + (size_t)row * DIN;
            float4 xf[8];
            #pragma unroll
            for (int j = 0; j < 4; ++j) {
                xf[j * 2 + 0] = *(const float4*)(xr + il * 8 + 128 * j);
                xf[j * 2 + 1] = *(const float4*)(xr + il * 8 + 128 * j + 4);
            }
            h2 xh[16];
            #pragma unroll
            for (int q = 0; q < 8; ++q) {
                xh[q * 2 + 0] = pack_h2(xf[q].x, xf[q].y);
                xh[q * 2 + 1] = pack_h2(xf[q].z, xf[q].w);
            }

            // ---- scores from LDS PW ----
            float sc[CC];
            #pragma unroll
            for (int c = 0; c < CC; ++c) sc[c] = 0.f;
            #pragma unroll
            for (int j = 0; j < 4; ++j) {
                #pragma unroll
                for (int c = 0; c < CC; ++c) {
                    uint4 pwb = *(const uint4*)&lds_pw[ci[c] * PWLD + j * 128 + il * 8];
                    h2 p0 = __builtin_bit_cast(h2, pwb.x);
                    h2 p1 = __builtin_bit_cast(h2, pwb.y);
                    h2 p2 = __builtin_bit_cast(h2, pwb.z);
                    h2 p3 = __builtin_bit_cast(h2, pwb.w);
                    float s = sc[c];
                    s = FDOT2(xh[j * 4 + 0], p0, s);
                    s = FDOT2(xh[j * 4 + 1], p1, s);
                    s = FDOT2(xh[j * 4 + 2], p2, s);
                    s = FDOT2(xh[j * 4 + 3], p3, s);
                    sc[c] = s;
                }
            }
            #pragma unroll
            for (int c = 0; c < CC; ++c) {
                float s = sc[c];
                s += __shfl_xor(s, 1);
                s += __shfl_xor(s, 2);
                s += __shfl_xor(s, 4);
                s += __shfl_xor(s, 8);
                sc[c] = s;
            }

            // ---- masked softmax (redundant per lane) ----
            float mx = -FLT_MAX;
            #pragma unroll
            for (int c = 0; c < CC; ++c)
                if (vm[c]) mx = fmaxf(mx, sc[c]);
            float e[CC], den = 0.f;
            #pragma unroll
            for (int c = 0; c < CC; ++c) {
                e[c] = vm[c] ? __expf(sc[c] - mx) : 0.f;
                den += e[c];
            }
            const float scale = 1.f / den;

            // ---- weighted PE sum from LDS ----
            float o[8];
            #pragma unroll
            for (int j = 0; j < 8; ++j) o[j] = 0.f;
            #pragma unroll
            for (int c = 0; c < CC; ++c) {
                const float w = e[c];
                uint4 peb = *(const uint4*)&lds_pe[ci[c] * PELD + il * 8];
                h2 q0 = __builtin_bit_cast(h2, peb.x);
                h2 q1 = __builtin_bit_cast(h2, peb.y);
                h2 q2 = __builtin_bit_cast(h2, peb.z);
                h2 q3 = __builtin_bit_cast(h2, peb.w);
                o[0] = fmaf(w, (float)q0[0], o[0]); o[1] = fmaf(w, (float)q0[1], o[1]);
                o[2] = fmaf(w, (float)q1[0], o[2]); o[3] = fmaf(w, (float)q1[1], o[3]);
                o[4] = fmaf(w, (float)q2[0], o[4]); o[5] = fmaf(w, (float)q2[1], o[5]);
                o[6] = fmaf(w, (float)q3[0], o[6]); o[7] = fmaf(w, (float)q3[1], o[7]);
            }

            *(float4*)op       = make_float4(o[0] * scale, o[1] * scale, o[2] * scale, o[3] * scale);
            *(float4*)(op + 4) = make_float4(o[4] * scale, o[5] * scale, o[6] * scale, o[7] * scale);
        }
    }
}

extern "C" void kernel_launch(void* const* d_in, const int* in_sizes, int n_in,
                              void* d_out, int out_size, void* d_ws, size_t ws_size,
                              hipStream_t stream) {
    const float* X  = (const float*)d_in[0];
    const float* W  = (const float*)d_in[1];
    const float* PE = (const float*)d_in[2];
    const int*   CI = (const int*)d_in[3];
    const int*   CM = (const int*)d_in[4];
    const int*   SL = (const int*)d_in[5];
    float* OUT = (float*)d_out;
    __half* PW  = (__half*)d_ws;                       // 96*512*2 = 96 KiB
    __half* PEh = (__half*)d_ws + (size_t)VV * DIN;    // +96*128*2 = 24 KiB

    hipLaunchKernelGGL(pw_kernel, dim3(VV, 4), dim3(128), 0, stream, W, PE, PW, PEh);

    const int rows = BB * LL;            // 65536
    hipLaunchKernelGGL(attn_kernel, dim3(rows / 256), dim3(1024), 0, stream,
                       X, PW, PEh, CI, CM, SL, OUT);
}